// Round 6
// baseline (75.095 us; speedup 1.0000x reference)
//
#include <hip/hip_runtime.h>
#include <stdint.h>

#define NMAX 16384
#define TT 1024
#define BB 16
#define CIN 512
#define DD 128
#define KH 4
#define NGRP 1024  // 16-row groups per k
#define INV_SQRT_D 0.08838834764831845f

typedef __attribute__((ext_vector_type(8))) short short8;
typedef __attribute__((ext_vector_type(4))) float f32x4;
typedef __attribute__((ext_vector_type(8))) int i32x8;

// ---------------- threefry2x32 (Random123 / JAX, 20 rounds) ----------------
__host__ __device__ static inline uint32_t rotl32(uint32_t x, int r) {
  return (x << r) | (x >> (32 - r));
}

__host__ __device__ static inline void tf_block(uint32_t k0, uint32_t k1,
                                                uint32_t& x0, uint32_t& x1) {
  uint32_t ks2 = k0 ^ k1 ^ 0x1BD11BDAu;
  x0 += k0; x1 += k1;
#define TF_R(r) { x0 += x1; x1 = rotl32(x1, (r)); x1 ^= x0; }
  TF_R(13) TF_R(15) TF_R(26) TF_R(6)
  x0 += k1; x1 += ks2 + 1u;
  TF_R(17) TF_R(29) TF_R(16) TF_R(24)
  x0 += ks2; x1 += k0 + 2u;
  TF_R(13) TF_R(15) TF_R(26) TF_R(6)
  x0 += k0; x1 += k1 + 3u;
  TF_R(17) TF_R(29) TF_R(16) TF_R(24)
  x0 += k1; x1 += ks2 + 4u;
  TF_R(13) TF_R(15) TF_R(26) TF_R(6)
  x0 += ks2; x1 += k0 + 5u;
#undef TF_R
}

struct TfKeys {
  uint32_t h0[KH], h1[KH];
};

// ------------------------------ helpers ------------------------------------
__device__ static inline ushort f2bf(float f) {
  uint32_t u = __float_as_uint(f);
  return (ushort)((u + 0x7FFFu + ((u >> 16) & 1u)) >> 16);
}

__device__ static inline unsigned char f2fp8(float f) {
  f = fminf(fmaxf(f, -448.f), 448.f);
  uint32_t u = __float_as_uint(f);
  uint32_t s = (u >> 24) & 0x80u;
  uint32_t mag = u & 0x7FFFFFFFu;
  if (mag < 0x3C800000u) return (unsigned char)s;
  mag += 0x7FFFFu + ((mag >> 20) & 1u);
  uint32_t e = (mag >> 23) - 120u;
  uint32_t m = (mag >> 20) & 7u;
  return (unsigned char)(s | (e << 3) | m);
}

__device__ static inline float fp8tof(uint32_t b) {
  const uint32_t mag = b & 0x7Fu;
  const uint32_t bits = ((b & 0x80u) << 24) | ((mag << 20) + 0x3C000000u);
  return mag ? __uint_as_float(bits) : 0.f;
}

__device__ static inline uint4 packA(float4 a0, float4 a1) {
  uint4 o;
  o.x = (uint32_t)f2bf(a0.x) | ((uint32_t)f2bf(a0.y) << 16);
  o.y = (uint32_t)f2bf(a0.z) | ((uint32_t)f2bf(a0.w) << 16);
  o.z = (uint32_t)f2bf(a1.x) | ((uint32_t)f2bf(a1.y) << 16);
  o.w = (uint32_t)f2bf(a1.z) | ((uint32_t)f2bf(a1.w) << 16);
  return o;
}

// ------------------- prep: idx gen + W pre-convert + out=0 ------------------
// blocks [0,1024): negatives. 128 shared per 16-row group; storage row
//   b*TT + t + k (the pop_left shift is folded into the stored row).
// blocks [1024,1280): W f32->bf16 in MFMA-fragment stream order:
//   wpre[s][step][wk][ni][lane] (uint4) = W_s[wk*128+ni*16+(lane&15)]
//                                          [step*32+(lane>>4)*8 .. +8]
__global__ __launch_bounds__(256) void prep_kernel(
    const float* __restrict__ Wq, const float* __restrict__ Wp,
    uint4* __restrict__ wpre, uint2* __restrict__ idx,
    float* __restrict__ out, TfKeys keys) {
  const int bid = blockIdx.x;
  const int tid = threadIdx.x;
  if (bid == 0 && tid == 0) out[0] = 0.f;
  if (bid < 1024) {
    const int k = bid >> 8;
    const uint32_t d = (uint32_t)(TT - k);
    const uint32_t span = (uint32_t)BB * d;
    const uint32_t md = 0xFFFFFFFFu / d + 1u;  // exact for n < 2^16
    const uint32_t i = (uint32_t)(bid & 255) * 256u + tid;
    uint32_t x0 = 0u, x1 = i;
    tf_block(keys.h0[k], keys.h1[k], x0, x1);
    const uint32_t j0 = x0 % span, j1 = x1 % span;
    const uint32_t b0 = (uint32_t)(((uint64_t)j0 * md) >> 32);
    const uint32_t b1 = (uint32_t)(((uint64_t)j1 * md) >> 32);
    idx[(size_t)k * (NGRP * 64) + i] =
        make_uint2(b0 * TT + (j0 - b0 * d) + k, b1 * TT + (j1 - b1 * d) + k);
  } else {
    const int t = (bid - 1024) * 256 + tid;  // uint4 index, 65536 total
    const int lane = t & 63;
    const int ni = (t >> 6) & 7;
    const int wk = (t >> 9) & 3;
    const int step = (t >> 11) & 15;
    const int s = t >> 15;
    const int row = wk * 128 + ni * 16 + (lane & 15);
    const int col = step * 32 + (lane >> 4) * 8;
    const float* W = (s ? Wp : Wq) + (size_t)row * CIN + col;
    wpre[t] = packA(((const float4*)W)[0], ((const float4*)W)[1]);
  }
}

// ------------------------- projection (MFMA GEMM) --------------------------
// Block: 256 thr = 4 waves, 64 input rows x all 4 horizons (wave wk = w).
// A (64x512 inputs) staged to LDS ONCE (one barrier total); W streamed
// global->VGPR per step in fragment order (L2-resident, coalesced 1KB bursts,
// one-step-ahead prefetch). NO barriers in the K-loop -> no vmcnt drain.
// Grid 512 blocks = 2 blocks/CU (LDS 2x65 KB).
__global__ __launch_bounds__(256, 2) void proj_kernel(
    const float* __restrict__ q, const float* __restrict__ p,
    const uint4* __restrict__ wpre,
    const float* __restrict__ bq, const float* __restrict__ bp,
    unsigned char* __restrict__ qh, unsigned char* __restrict__ ph) {
  const int pr = blockIdx.y;
  const float* src = pr ? p : q;
  const float* bias = pr ? bp : bq;
  unsigned char* dst = pr ? ph : qh;
  const int n0 = blockIdx.x * 64;
  const int tid = threadIdx.x;
  const int lane = tid & 63;
  const int wk = tid >> 6;
  const int g = lane >> 4, frow = lane & 15;

  __shared__ ushort lds_a[64][520];  // 64 rows x 512 k bf16, +8 pad

  // ---- stage A once: tile is one contiguous 128 KB block of src ----
  const float* abase = src + (size_t)n0 * CIN;
#pragma unroll
  for (int i = 0; i < 16; ++i) {
    const int f = (i * 256 + tid) * 8;  // flat float idx; 8 floats/thread/iter
    const float4 v0 = *(const float4*)(abase + f);
    const float4 v1 = *(const float4*)(abase + f + 4);
    *(uint4*)&lds_a[f >> 9][f & 511] = packA(v0, v1);
  }
  __syncthreads();  // the only barrier

  const uint4* wp = wpre + ((size_t)(pr * 64 + wk) * 8) * 64 + lane;
  // step stride = 4 wk * 8 ni * 64 lanes = 2048 uint4

  f32x4 acc[8][4];
#pragma unroll
  for (int ni = 0; ni < 8; ++ni)
#pragma unroll
    for (int mi = 0; mi < 4; ++mi)
      acc[ni][mi] = (f32x4){0.f, 0.f, 0.f, 0.f};

  union WF { uint4 u; short8 s; };
  WF wf[8], wfn[8];
#pragma unroll
  for (int ni = 0; ni < 8; ++ni) wf[ni].u = wp[ni * 64];

#pragma unroll
  for (int st = 0; st < 16; ++st) {
    if (st < 15) {
      const uint4* wpn = wp + (size_t)(st + 1) * 2048;
#pragma unroll
      for (int ni = 0; ni < 8; ++ni) wfn[ni].u = wpn[ni * 64];  // prefetch
    }
    short8 inf[4];
#pragma unroll
    for (int mi = 0; mi < 4; ++mi)
      inf[mi] = *(const short8*)&lds_a[mi * 16 + frow][st * 32 + g * 8];
#pragma unroll
    for (int ni = 0; ni < 8; ++ni)
#pragma unroll
      for (int mi = 0; mi < 4; ++mi)
        acc[ni][mi] = __builtin_amdgcn_mfma_f32_16x16x32_bf16(wf[ni].s, inf[mi],
                                                              acc[ni][mi], 0, 0, 0);
#pragma unroll
    for (int ni = 0; ni < 8; ++ni) wf[ni] = wfn[ni];
  }

  // epilogue: D col(lane&15)=input row, row((lane>>4)*4+r)=d  [m89-verified]
  unsigned char* dk = dst + (size_t)wk * NMAX * DD;
#pragma unroll
  for (int ni = 0; ni < 8; ++ni) {
    const int d0 = ni * 16 + g * 4;
    const float4 bv = *(const float4*)(bias + wk * DD + d0);
#pragma unroll
    for (int mi = 0; mi < 4; ++mi) {
      const int n = n0 + mi * 16 + frow;
      const uint32_t pk = (uint32_t)f2fp8(acc[ni][mi][0] + bv.x) |
                          ((uint32_t)f2fp8(acc[ni][mi][1] + bv.y) << 8) |
                          ((uint32_t)f2fp8(acc[ni][mi][2] + bv.z) << 16) |
                          ((uint32_t)f2fp8(acc[ni][mi][3] + bv.w) << 24);
      *(uint32_t*)(dk + (size_t)n * DD + d0) = pk;
    }
  }
}

// ------------------------------- loss (fp8 MFMA) ----------------------------
// One wave = one 16-row group sharing 128 negatives; 8 neg tiles of
// mfma_scale 16x16x128 (unit scales). Positive via layout-free VALU fp8 dot.
// Per-block sum + one atomicAdd (out zeroed in prep).
__global__ __launch_bounds__(256) void loss_kernel(
    const unsigned char* __restrict__ qh, const unsigned char* __restrict__ ph,
    const int* __restrict__ idx, float* __restrict__ out) {
  const int tid = threadIdx.x;
  const int lane = tid & 63;
  const int k = blockIdx.y;
  const int grp0 = blockIdx.x * 4 + (tid >> 6);
  const bool valid = grp0 < NGRP - k;
  const int grp = valid ? grp0 : 0;
  const int g = lane >> 4;
  const int r16 = lane & 15;

  const uint32_t d = (uint32_t)(TT - k);
  const uint32_t md = 0xFFFFFFFFu / d + 1u;
  const uint32_t n = (uint32_t)(grp * 16 + r16);
  const uint32_t b = (uint32_t)(((uint64_t)n * md) >> 32);
  const uint32_t rowq = b * TT + (n - b * d);

  const unsigned char* qbase = qh + (size_t)k * NMAX * DD;
  const unsigned char* pbase = ph + (size_t)k * NMAX * DD;
  const int* irow = idx + (size_t)k * (NGRP * 128) + grp * 128 + r16 * 8;

  union Frag { uint4 u[2]; i32x8 v; uint32_t w[8]; };
  Frag bq8;
  bq8.u[0] = ((const uint4*)(qbase + (size_t)rowq * DD + g * 32))[0];
  bq8.u[1] = ((const uint4*)(qbase + (size_t)rowq * DD + g * 32))[1];

  const int4 iv0 = ((const int4*)irow)[0];
  const int4 iv1 = ((const int4*)irow)[1];
  const int js[8] = {iv0.x, iv0.y, iv0.z, iv0.w, iv1.x, iv1.y, iv1.z, iv1.w};

  const f32x4 zero = (f32x4){0.f, 0.f, 0.f, 0.f};
  f32x4 acc[8];
#pragma unroll
  for (int t = 0; t < 8; ++t) {
    const unsigned char* prow = pbase + (size_t)js[t] * DD + g * 32;
    Frag a8;
    a8.u[0] = ((const uint4*)prow)[0];
    a8.u[1] = ((const uint4*)prow)[1];
    acc[t] = __builtin_amdgcn_mfma_scale_f32_16x16x128_f8f6f4(
        a8.v, bq8.v, zero, 0, 0, 0, 0x7F, 0, 0x7F);
  }

  Frag pp8;
  pp8.u[0] = ((const uint4*)(pbase + (size_t)(rowq + k) * DD + g * 32))[0];
  pp8.u[1] = ((const uint4*)(pbase + (size_t)(rowq + k) * DD + g * 32))[1];
  float pp = 0.f;
#pragma unroll
  for (int wd = 0; wd < 8; ++wd) {
    const uint32_t aw = pp8.w[wd], qw = bq8.w[wd];
#pragma unroll
    for (int by = 0; by < 4; ++by)
      pp = fmaf(fp8tof((aw >> (8 * by)) & 0xFFu), fp8tof((qw >> (8 * by)) & 0xFFu), pp);
  }
  pp += __shfl_xor(pp, 16);
  pp += __shfl_xor(pp, 32);

  float m = pp;
#pragma unroll
  for (int t = 0; t < 8; ++t)
#pragma unroll
    for (int r = 0; r < 4; ++r) m = fmaxf(m, acc[t][r]);
  m = fmaxf(m, __shfl_xor(m, 16));
  m = fmaxf(m, __shfl_xor(m, 32));
  const float gm = m * INV_SQRT_D;

  float s = 0.f;
#pragma unroll
  for (int t = 0; t < 8; ++t)
#pragma unroll
    for (int r = 0; r < 4; ++r) s += __expf(acc[t][r] * INV_SQRT_D - gm);
  s += __shfl_xor(s, 16);
  s += __shfl_xor(s, 32);
  const float l0 = pp * INV_SQRT_D;
  s += __expf(l0 - gm);

  float lr = gm + __logf(s) - l0;
  lr = (valid && g == 0) ? lr : 0.f;
#pragma unroll
  for (int off = 32; off; off >>= 1) lr += __shfl_xor(lr, off);
  __shared__ float bsum[4];
  if (lane == 0) bsum[tid >> 6] = lr;
  __syncthreads();
  if (tid == 0) atomicAdd(out, (bsum[0] + bsum[1]) + (bsum[2] + bsum[3]));
}

// ------------------------------ launcher -----------------------------------
extern "C" void kernel_launch(void* const* d_in, const int* in_sizes, int n_in,
                              void* d_out, int out_size, void* d_ws, size_t ws_size,
                              hipStream_t stream) {
  const float* q = (const float*)d_in[0];
  const float* p = (const float*)d_in[1];
  const float* Wq = (const float*)d_in[2];
  const float* bq = (const float*)d_in[3];
  const float* Wp = (const float*)d_in[4];
  const float* bp = (const float*)d_in[5];
  float* out = (float*)d_out;

  char* ws = (char*)d_ws;
  const size_t sz_proj = (size_t)KH * NMAX * DD;       // 8.39 MB (fp8)
  unsigned char* qh = (unsigned char*)ws;
  unsigned char* ph = (unsigned char*)(ws + sz_proj);
  int* idxbuf = (int*)(ws + 2 * sz_proj);              // 2 MB
  uint4* wpre = (uint4*)(ws + 2 * sz_proj + (size_t)KH * NGRP * 128 * sizeof(int));  // 1 MB

  TfKeys keys;
  for (int k = 0; k < KH; ++k) {
    uint32_t f0 = 0u, f1 = (uint32_t)k;
    tf_block(0u, 42u, f0, f1);  // fold_in: threefry(key(42), [0, k])
    uint32_t a0 = 0u, a1 = 2u;
    tf_block(f0, f1, a0, a1);
    uint32_t c0 = 1u, c1 = 3u;
    tf_block(f0, f1, c0, c1);
    keys.h0[k] = a0; keys.h1[k] = c0;
  }

  prep_kernel<<<1280, 256, 0, stream>>>(Wq, Wp, wpre, (uint2*)idxbuf, out, keys);
  proj_kernel<<<dim3(NMAX / 64, 2), 256, 0, stream>>>(q, p, wpre, bq, bp, qh, ph);
  loss_kernel<<<dim3(NGRP / 4, KH), 256, 0, stream>>>(qh, ph, idxbuf, out);
}